// Round 1
// 2664.838 us; speedup vs baseline: 1.4288x; 1.4288x over previous
//
#include <hip/hip_runtime.h>
#include <math.h>

constexpr int Bc = 4, Nc = 32768, Cc = 256, Hc = 8, CHc = 64, Mc = 64, INNERc = 512;

typedef _Float16 h8 __attribute__((ext_vector_type(8)));
typedef float f32x4 __attribute__((ext_vector_type(4)));

__device__ __forceinline__ void fma4x4(float acc[4][4], const float4 a, const float4 b) {
  acc[0][0] += a.x*b.x; acc[0][1] += a.x*b.y; acc[0][2] += a.x*b.z; acc[0][3] += a.x*b.w;
  acc[1][0] += a.y*b.x; acc[1][1] += a.y*b.y; acc[1][2] += a.y*b.z; acc[1][3] += a.y*b.w;
  acc[2][0] += a.z*b.x; acc[2][1] += a.z*b.y; acc[2][2] += a.z*b.z; acc[2][3] += a.z*b.w;
  acc[3][0] += a.w*b.x; acc[3][1] += a.w*b.y; acc[3][2] += a.w*b.z; acc[3][3] += a.w*b.w;
}

// ============================================================================
// project_token: per (chunk, h, b): for each 64-token tile:
//   STAGE 1 (NEW, MFMA f16x3): FX|XM (64 tok x 128 col) = X @ [Wfx_h | Wx_h]
//     - wave w owns 32 cols; its W panel (256K x 32col, f16 hi/lo frags) lives
//       in 128 VGPRs, loaded ONCE per block (reused across all 32 tiles).
//     - X staged per 32-K chunk as f16 hi/lo in LDS (8 KB, overlaid on smem).
//     - C = Ah*Bh + Al*Bh + Ah*Bl  (error ~2^-21 rel; fp32 accumulate).
//   STAGE 2-4 (unchanged fp32): logits = XM@Wslice, softmax over g,
//     TUacc[g][c] += sum_t sw[t][g]*FX[t][c]; Ssum[g] += sum_t sw[t][g]
// LDS overlay (192 rows x 68 f32 = 52,224 B):
//   rows 0..31  Xh/Xl f16 staging (stage 1 only, dead before FXs written)
//   rows 0..63  FXs[token][c] | 64..127 XMs[c][token] -> Lg[token][g]
//   rows 128..191 Ws2 (Wslice, persistent; reused as Ssum tmp at end)
// ============================================================================
__global__ __launch_bounds__(256, 2)
void project_token_kernel(const float* __restrict__ X, const float* __restrict__ Wfx,
                          const float* __restrict__ bfx, const float* __restrict__ Wx,
                          const float* __restrict__ bx, const float* __restrict__ Wsl,
                          const float* __restrict__ bsl, const float* __restrict__ temp,
                          float* __restrict__ TU, float* __restrict__ Ssum)
{
  __shared__ __align__(16) float smem[192 * 68];  // 52,224 B
  float (*FXs)[68] = (float(*)[68])smem;                 // [token][c]
  float (*XMs)[68] = (float(*)[68])(smem + 64*68);       // [c][token]
  float (*Lg)[68]  = (float(*)[68])(smem + 64*68);       // [token][g]
  float (*Ws2)[68] = (float(*)[68])(smem + 128*68);
  _Float16* Xh = (_Float16*)smem;                        // [64][32] f16 (2048 = 1024 f32)
  _Float16* Xl = (_Float16*)(smem + 1024);               // [64][32] f16

  const int t = threadIdx.x, tx = t & 15, ty = t >> 4;
  const int chunk = blockIdx.x, h = blockIdx.y, b = blockIdx.z;
  const int bh = b * Hc + h, colBase = h * 64;
  const int w = t >> 6, l = t & 63;                      // wave id, lane id
  const int lg = l >> 4, lr = l & 15;                    // lane group / lane row
  const int stok = t >> 2, sc8 = (t & 3) << 3;           // X staging map: tok, c-octet

  // Wslice persistent in LDS
#pragma unroll
  for (int rep = 0; rep < 4; ++rep) {
    const int v = t + rep * 256, r = v >> 4, c4 = (v & 15) << 2;
    *(float4*)&Ws2[r][c4] = *(const float4*)&Wsl[r * 64 + c4];
  }
  const float invt = 1.0f / fminf(fmaxf(temp[h], 0.1f), 5.0f);
  const float4 bsv = *(const float4*)&bsl[(tx << 2)];
  const float bs_[4] = {bsv.x, bsv.y, bsv.z, bsv.w};

  // ---- W panel for this wave's 32 cols, f16 hi/lo fragments in registers ----
  // waves 0,1 -> Wfx cols [w*32, w*32+32); waves 2,3 -> Wx cols [(w-2)*32, ...)
  const float* Wsrc = (w < 2) ? Wfx : Wx;
  const float* bsrc = (w < 2) ? bfx : bx;
  const int wcb = colBase + ((w & 1) << 5);
  h8 wfh[8][2], wfl[8][2];   // [kstep][n-tile], 128 VGPR total
  float biasv[2];
#pragma unroll
  for (int n = 0; n < 2; ++n) {
    const int col = wcb + (n << 4) + lr;
    biasv[n] = bsrc[col];
#pragma unroll
    for (int ks = 0; ks < 8; ++ks) {
#pragma unroll
      for (int j = 0; j < 8; ++j) {
        // element j <-> k = ks*32 + lg*8 + j  (same placement convention as A)
        const float v = Wsrc[(long)((ks << 5) + (lg << 3) + j) * INNERc + col];
        const _Float16 hi = (_Float16)v;
        wfh[ks][n][j] = hi;
        wfl[ks][n][j] = (_Float16)(v - (float)hi);
      }
    }
  }

  float tuacc[4][4] = {};
  float sreg[4] = {};

  for (int tile = 0; tile < 32; ++tile) {
    const int n0 = chunk * 2048 + tile * 64;
    const long xBase = ((long)b * Nc + n0) * Cc;
    const long xRow = xBase + (long)stok * Cc + sc8;

    // ---- stage 1: MFMA f16x3 GEMM over K=256 in 8 chunks of 32 ----
    f32x4 acc[4][2] = {};
    float4 xa = *(const float4*)&X[xRow];
    float4 xb = *(const float4*)&X[xRow + 4];
#pragma unroll
    for (int ks = 0; ks < 8; ++ks) {
      h8 hv, lv;
      const float va[8] = {xa.x, xa.y, xa.z, xa.w, xb.x, xb.y, xb.z, xb.w};
#pragma unroll
      for (int j = 0; j < 8; ++j) {
        const _Float16 hi = (_Float16)va[j];
        hv[j] = hi;
        lv[j] = (_Float16)(va[j] - (float)hi);
      }
      __syncthreads();  // prev kstep frag reads / prev tile stage-4 FXs+Lg reads done
      *(h8*)&Xh[(stok << 5) + sc8] = hv;
      *(h8*)&Xl[(stok << 5) + sc8] = lv;
      __syncthreads();
      if (ks < 7) {     // prefetch next K-chunk under the MFMAs
        xa = *(const float4*)&X[xRow + ((ks + 1) << 5)];
        xb = *(const float4*)&X[xRow + ((ks + 1) << 5) + 4];
      }
#pragma unroll
      for (int m = 0; m < 4; ++m) {
        const h8 ah = *(const h8*)&Xh[(((m << 4) + lr) << 5) + (lg << 3)];
        const h8 al = *(const h8*)&Xl[(((m << 4) + lr) << 5) + (lg << 3)];
#pragma unroll
        for (int n = 0; n < 2; ++n) {
          acc[m][n] = __builtin_amdgcn_mfma_f32_16x16x32_f16(ah, wfh[ks][n], acc[m][n], 0, 0, 0);
          acc[m][n] = __builtin_amdgcn_mfma_f32_16x16x32_f16(al, wfh[ks][n], acc[m][n], 0, 0, 0);
          acc[m][n] = __builtin_amdgcn_mfma_f32_16x16x32_f16(ah, wfl[ks][n], acc[m][n], 0, 0, 0);
        }
      }
    }
    __syncthreads();  // all frag reads done before FXs/XMs overlay writes

    // C layout: col = lane&15, row = 4*(lane>>4) + reg  [HW-verified]
    if (w < 2) {
#pragma unroll
      for (int m = 0; m < 4; ++m)
#pragma unroll
        for (int n = 0; n < 2; ++n) {
          const int c = ((w & 1) << 5) + (n << 4) + lr;
          const int tokb = (m << 4) + (lg << 2);
#pragma unroll
          for (int i = 0; i < 4; ++i) FXs[tokb + i][c] = acc[m][n][i] + biasv[n];
        }
    } else {
#pragma unroll
      for (int m = 0; m < 4; ++m)
#pragma unroll
        for (int n = 0; n < 2; ++n) {
          const int c = ((w & 1) << 5) + (n << 4) + lr;
          const int tokb = (m << 4) + (lg << 2);
#pragma unroll
          for (int i = 0; i < 4; ++i) XMs[c][tokb + i] = acc[m][n][i] + biasv[n];  // [c][token]
        }
    }
    __syncthreads();

    // ---- stage 2: logits[token][g] = XM @ Wslice (contract over c=k) ----
    float l2[4][4] = {};
#pragma unroll
    for (int k = 0; k < 64; ++k) {
      const float4 a = *(const float4*)&XMs[k][ty << 2];   // token quad at channel k
      fma4x4(l2, a, *(const float4*)&Ws2[k][tx << 2]);     // Wsl[c=k][g quad]
    }
    // ---- stage 3: softmax over g (row = 16-lane shfl group, 4 rows/thread) ----
    float e[4][4];
#pragma unroll
    for (int i = 0; i < 4; ++i) {
      float mx = -1e30f;
#pragma unroll
      for (int j = 0; j < 4; ++j) { l2[i][j] = (l2[i][j] + bs_[j]) * invt; mx = fmaxf(mx, l2[i][j]); }
      for (int d = 1; d < 16; d <<= 1) mx = fmaxf(mx, __shfl_xor(mx, d));
      float s = 0.f;
#pragma unroll
      for (int j = 0; j < 4; ++j) { e[i][j] = __expf(l2[i][j] - mx); s += e[i][j]; }
      for (int d = 1; d < 16; d <<= 1) s += __shfl_xor(s, d);
      const float inv = 1.0f / s;
#pragma unroll
      for (int j = 0; j < 4; ++j) { e[i][j] *= inv; sreg[j] += e[i][j]; }
    }
    __syncthreads();  // XMs reads done before Lg overlay write
#pragma unroll
    for (int i = 0; i < 4; ++i)
#pragma unroll
      for (int j = 0; j < 4; ++j) Lg[(ty<<2)+i][(tx<<2)+j] = e[i][j];
    __syncthreads();

    // ---- stage 4: TU contraction (contract over token=k) ----
#pragma unroll
    for (int k = 0; k < 64; ++k) {
      const float4 a = *(const float4*)&Lg[k][ty << 2];     // g quad
      fma4x4(tuacc, a, *(const float4*)&FXs[k][tx << 2]);   // c quad
    }
  }

#pragma unroll
  for (int i = 0; i < 4; ++i)
#pragma unroll
    for (int j = 0; j < 4; ++j)
      atomicAdd(&TU[((long)bh * 64 + (ty<<2)+i) * 64 + (tx<<2)+j], tuacc[i][j]);

  // Ssum reduce over ty (reuse Ws2 rows as tmp)
  __syncthreads();
#pragma unroll
  for (int j = 0; j < 4; ++j) Ws2[ty][(tx<<2)+j] = sreg[j];
  __syncthreads();
  if (t < 64) {
    float s = 0.f;
    for (int r = 0; r < 16; ++r) s += Ws2[r][t];
    atomicAdd(&Ssum[bh * 64 + t], s);
  }
}

// ============================================================================
// att: 32 blocks x 1 wave. token = TU/(S+eps); q/k/v; softmax attention;
// writes OT[bh][c][g] = out_tok[g][c] / (Sx[g]+eps)   (invx folded for out einsum)
// ============================================================================
__global__ __launch_bounds__(64)
void att_kernel(const float* __restrict__ TUx, const float* __restrict__ TUc,
                const float* __restrict__ Sx, const float* __restrict__ Sc,
                const float* __restrict__ Wq, const float* __restrict__ Wk,
                const float* __restrict__ Wv, float* __restrict__ OT)
{
  __shared__ __align__(16) float W[64][68];
  __shared__ __align__(16) float Km[64][68];
  __shared__ __align__(16) float Vm[64][68];
  const int bh = blockIdx.x;
  const int g  = threadIdx.x;
  const float invc = 1.0f / (Sc[bh * 64 + g] + 1e-5f);
  const float invx = 1.0f / (Sx[bh * 64 + g] + 1e-5f);

  // K = token_c @ Wk
  for (int i = 0; i < 64; ++i) W[i][g] = Wk[i * 64 + g];
  __syncthreads();
  {
    float4 a[16]; for (int j = 0; j < 16; ++j) a[j] = make_float4(0,0,0,0);
    for (int c = 0; c < 64; ++c) {
      const float tc = TUc[((long)bh * 64 + g) * 64 + c] * invc;
#pragma unroll
      for (int j = 0; j < 16; ++j) {
        const float4 w4 = *(const float4*)&W[c][j << 2];
        a[j].x += tc*w4.x; a[j].y += tc*w4.y; a[j].z += tc*w4.z; a[j].w += tc*w4.w;
      }
    }
    for (int j = 0; j < 16; ++j) *(float4*)&Km[g][j << 2] = a[j];
  }
  __syncthreads();
  // V = token_c @ Wv
  for (int i = 0; i < 64; ++i) W[i][g] = Wv[i * 64 + g];
  __syncthreads();
  {
    float4 a[16]; for (int j = 0; j < 16; ++j) a[j] = make_float4(0,0,0,0);
    for (int c = 0; c < 64; ++c) {
      const float tc = TUc[((long)bh * 64 + g) * 64 + c] * invc;
#pragma unroll
      for (int j = 0; j < 16; ++j) {
        const float4 w4 = *(const float4*)&W[c][j << 2];
        a[j].x += tc*w4.x; a[j].y += tc*w4.y; a[j].z += tc*w4.z; a[j].w += tc*w4.w;
      }
    }
    for (int j = 0; j < 16; ++j) *(float4*)&Vm[g][j << 2] = a[j];
  }
  __syncthreads();
  // Q = token_x @ Wq (kept in regs)
  for (int i = 0; i < 64; ++i) W[i][g] = Wq[i * 64 + g];
  __syncthreads();
  float4 qa[16]; for (int j = 0; j < 16; ++j) qa[j] = make_float4(0,0,0,0);
  for (int c = 0; c < 64; ++c) {
    const float tq = TUx[((long)bh * 64 + g) * 64 + c] * invx;
#pragma unroll
    for (int j = 0; j < 16; ++j) {
      const float4 w4 = *(const float4*)&W[c][j << 2];
      qa[j].x += tq*w4.x; qa[j].y += tq*w4.y; qa[j].z += tq*w4.z; qa[j].w += tq*w4.w;
    }
  }
  __syncthreads();  // all W reads done; overlay Am on W
  float (*Am)[68] = W;
  float mx = -1e30f;
  for (int m = 0; m < 64; ++m) {
    float s = 0.f;
#pragma unroll
    for (int j = 0; j < 16; ++j) {
      const float4 k4 = *(const float4*)&Km[m][j << 2];
      s += qa[j].x*k4.x + qa[j].y*k4.y + qa[j].z*k4.z + qa[j].w*k4.w;
    }
    s *= 0.125f;               // CH^-0.5
    Am[m][g] = s;              // per-thread column, no cross-thread use
    mx = fmaxf(mx, s);
  }
  float sum = 0.f;
  for (int m = 0; m < 64; ++m) { const float ev = __expf(Am[m][g] - mx); Am[m][g] = ev; sum += ev; }
  float4 oa[16]; for (int j = 0; j < 16; ++j) oa[j] = make_float4(0,0,0,0);
  for (int m = 0; m < 64; ++m) {
    const float am = Am[m][g];
#pragma unroll
    for (int j = 0; j < 16; ++j) {
      const float4 v4 = *(const float4*)&Vm[m][j << 2];
      oa[j].x += am*v4.x; oa[j].y += am*v4.y; oa[j].z += am*v4.z; oa[j].w += am*v4.w;
    }
  }
  const float so = invx / sum;
#pragma unroll
  for (int j = 0; j < 16; ++j) {
    OT[((long)bh * 64 + ((j<<2)+0)) * 64 + g] = oa[j].x * so;
    OT[((long)bh * 64 + ((j<<2)+1)) * 64 + g] = oa[j].y * so;
    OT[((long)bh * 64 + ((j<<2)+2)) * 64 + g] = oa[j].z * so;
    OT[((long)bh * 64 + ((j<<2)+3)) * 64 + g] = oa[j].w * so;
  }
}

// ============================================================================
// wofold: WoT[bh][g][co] = sum_c OT[bh][c][g] * Wo[h*64+c][co]
// ============================================================================
__global__ __launch_bounds__(256)
void wofold_kernel(const float* __restrict__ OT, const float* __restrict__ Wo,
                   float* __restrict__ WoT)
{
  __shared__ __align__(16) float OTs[64][68];
  __shared__ __align__(16) float Wos[64][68];
  const int t = threadIdx.x, tx = t & 15, ty = t >> 4;
  const int cot = blockIdx.x * 64, bh = blockIdx.y, h = bh & 7;
#pragma unroll
  for (int rep = 0; rep < 4; ++rep) {
    const int v = t + rep * 256, r = v >> 4, q4 = (v & 15) << 2;
    *(float4*)&OTs[r][q4] = *(const float4*)&OT[((long)bh * 64 + r) * 64 + q4];
    *(float4*)&Wos[r][q4] = *(const float4*)&Wo[(long)(h * 64 + r) * 256 + cot + q4];
  }
  __syncthreads();
  float acc[4][4] = {};
#pragma unroll
  for (int k = 0; k < 64; ++k) {
    const float4 a = *(const float4*)&OTs[k][ty << 2];   // g quad
    fma4x4(acc, a, *(const float4*)&Wos[k][tx << 2]);    // co quad
  }
#pragma unroll
  for (int i = 0; i < 4; ++i) {
    const float4 o = make_float4(acc[i][0], acc[i][1], acc[i][2], acc[i][3]);
    *(float4*)&WoT[((long)bh * 64 + (ty<<2)+i) * 256 + cot + (tx<<2)] = o;
  }
}

// ============================================================================
// outx: per (ntile, b): recompute sw_x per head, contract with WoT:
//   out[n][co] = bo[co] + sum_h sum_g sw_raw[n][g] * WoT[bh][g][co]
// ============================================================================
__global__ __launch_bounds__(256)
void outx_kernel(const float* __restrict__ X, const float* __restrict__ Wx,
                 const float* __restrict__ bx, const float* __restrict__ Wsl,
                 const float* __restrict__ bsl, const float* __restrict__ temp,
                 const float* __restrict__ WoT, const float* __restrict__ bo,
                 float* __restrict__ out)
{
  __shared__ __align__(16) float smem[192 * 68];
  float (*As)[68]  = (float(*)[68])smem;
  float (*Bs)[68]  = (float(*)[68])(smem + 32*68);
  float (*XMs)[68] = (float(*)[68])(smem + 64*68);  // [c][token]
  float (*LgT)[68] = (float(*)[68])(smem + 64*68);  // [g][token]
  float (*Ws2)[68] = (float(*)[68])(smem + 128*68);
  float (*WTs)[264] = (float(*)[264])smem;           // 16x264 <= 64x68 region

  const int t = threadIdx.x, tx = t & 15, ty = t >> 4;
  const int n0 = blockIdx.x * 64, b = blockIdx.y;
  const int lr = t >> 3, lk = (t & 7) << 2;
  const int wk = t >> 4, wc = (t & 15) << 2;
  const long xBase = ((long)b * Nc + n0) * Cc;

#pragma unroll
  for (int rep = 0; rep < 4; ++rep) {
    const int v = t + rep * 256, r = v >> 4, c4 = (v & 15) << 2;
    *(float4*)&Ws2[r][c4] = *(const float4*)&Wsl[r * 64 + c4];
  }
  const float4 bsv = *(const float4*)&bsl[(tx << 2)];
  const float bs_[4] = {bsv.x, bsv.y, bsv.z, bsv.w};

  float4 acc4[4][4] = {};  // [i(tok)][q] over co quad

  for (int h = 0; h < Hc; ++h) {
    const int bh = b * Hc + h, colBase = h * 64;
    const float invt = 1.0f / fminf(fmaxf(temp[h], 0.1f), 5.0f);
    const float4 bxv = *(const float4*)&bx[colBase + (tx << 2)];
    const float bx_[4] = {bxv.x, bxv.y, bxv.z, bxv.w};

    // ---- stage 1: XM = X@Wx_h + bx ----
    float a1[4][4] = {};
    for (int kt = 0; kt < Cc; kt += 32) {
      const float4 x0 = *(const float4*)&X[xBase + (long)lr        * Cc + kt + lk];
      const float4 x1 = *(const float4*)&X[xBase + (long)(lr + 32) * Cc + kt + lk];
      const float4 g0 = *(const float4*)&Wx[(long)(kt + wk)      * INNERc + colBase + wc];
      const float4 g1 = *(const float4*)&Wx[(long)(kt + wk + 16) * INNERc + colBase + wc];
      __syncthreads();  // guards prev head's WTs/LgT reads vs As/Bs overwrite
      As[lk+0][lr] = x0.x; As[lk+1][lr] = x0.y; As[lk+2][lr] = x0.z; As[lk+3][lr] = x0.w;
      As[lk+0][lr+32] = x1.x; As[lk+1][lr+32] = x1.y; As[lk+2][lr+32] = x1.z; As[lk+3][lr+32] = x1.w;
      *(float4*)&Bs[wk][wc] = g0; *(float4*)&Bs[wk+16][wc] = g1;
      __syncthreads();
#pragma unroll
      for (int k = 0; k < 32; ++k) {
        const float4 a = *(const float4*)&As[k][ty << 2];
        fma4x4(a1, a, *(const float4*)&Bs[k][tx << 2]);
      }
    }
    __syncthreads();
#pragma unroll
    for (int i = 0; i < 4; ++i)
#pragma unroll
      for (int j = 0; j < 4; ++j)
        XMs[(tx<<2)+j][(ty<<2)+i] = a1[i][j] + bx_[j];   // [c][token]  (transposed!)
    __syncthreads();

    // ---- logits (contract over c=k) + softmax ----
    float l2[4][4] = {};
#pragma unroll
    for (int k = 0; k < 64; ++k) {
      const float4 a = *(const float4*)&XMs[k][ty << 2];
      fma4x4(l2, a, *(const float4*)&Ws2[k][tx << 2]);
    }
    float e[4][4];
#pragma unroll
    for (int i = 0; i < 4; ++i) {
      float mx = -1e30f;
#pragma unroll
      for (int j = 0; j < 4; ++j) { l2[i][j] = (l2[i][j] + bs_[j]) * invt; mx = fmaxf(mx, l2[i][j]); }
      for (int d = 1; d < 16; d <<= 1) mx = fmaxf(mx, __shfl_xor(mx, d));
      float s = 0.f;
#pragma unroll
      for (int j = 0; j < 4; ++j) { e[i][j] = __expf(l2[i][j] - mx); s += e[i][j]; }
      for (int d = 1; d < 16; d <<= 1) s += __shfl_xor(s, d);
      const float inv = 1.0f / s;
#pragma unroll
      for (int j = 0; j < 4; ++j) e[i][j] *= inv;
    }
    __syncthreads();  // XMs reads done before LgT overlay
#pragma unroll
    for (int i = 0; i < 4; ++i)
#pragma unroll
      for (int j = 0; j < 4; ++j)
        LgT[(tx<<2)+j][(ty<<2)+i] = e[i][j];   // [g][tok]
    __syncthreads();

    // ---- contract with WoT[bh] in g-chunks of 16 ----
    for (int gc = 0; gc < 4; ++gc) {
#pragma unroll
      for (int rep = 0; rep < 4; ++rep) {
        const int idx = t + rep * 256;           // 0..1023
        const int r = idx >> 6, q = (idx & 63) << 2;
        *(float4*)&WTs[r][q] = *(const float4*)&WoT[((long)bh * 64 + (gc<<4) + r) * 256 + q];
      }
      __syncthreads();
#pragma unroll
      for (int k = 0; k < 16; ++k) {
        const float4 a = *(const float4*)&LgT[(gc<<4) + k][ty << 2];
        const float av[4] = {a.x, a.y, a.z, a.w};
#pragma unroll
        for (int q = 0; q < 4; ++q) {
          const float4 w4 = *(const float4*)&WTs[k][(q<<6) + (tx<<2)];
#pragma unroll
          for (int i = 0; i < 4; ++i) {
            acc4[i][q].x += av[i]*w4.x; acc4[i][q].y += av[i]*w4.y;
            acc4[i][q].z += av[i]*w4.z; acc4[i][q].w += av[i]*w4.w;
          }
        }
      }
      __syncthreads();  // WTs reads done before next gc reload
    }
  }

#pragma unroll
  for (int q = 0; q < 4; ++q) {
    const float4 bov = *(const float4*)&bo[(q<<6) + (tx<<2)];
#pragma unroll
    for (int i = 0; i < 4; ++i) {
      float4 o;
      o.x = acc4[i][q].x + bov.x; o.y = acc4[i][q].y + bov.y;
      o.z = acc4[i][q].z + bov.z; o.w = acc4[i][q].w + bov.w;
      *(float4*)&out[((long)b * Nc + n0 + (ty<<2)+i) * 256 + (q<<6) + (tx<<2)] = o;
    }
  }
}

extern "C" void kernel_launch(void* const* d_in, const int* in_sizes, int n_in,
                              void* d_out, int out_size, void* d_ws, size_t ws_size,
                              hipStream_t stream)
{
  (void)in_sizes; (void)n_in; (void)out_size; (void)ws_size;
  const float* x    = (const float*)d_in[0];
  const float* xc   = (const float*)d_in[1];
  const float* Wfx  = (const float*)d_in[2];
  const float* bfx  = (const float*)d_in[3];
  const float* Wx   = (const float*)d_in[4];
  const float* bx   = (const float*)d_in[5];
  const float* Wsl  = (const float*)d_in[6];
  const float* bsl  = (const float*)d_in[7];
  const float* temp = (const float*)d_in[8];
  const float* Wq   = (const float*)d_in[9];
  const float* Wk   = (const float*)d_in[10];
  const float* Wv   = (const float*)d_in[11];
  const float* Wo   = (const float*)d_in[12];
  const float* bo   = (const float*)d_in[13];
  float* out = (float*)d_out;

  // workspace: 921,600 floats = 3.69 MB total
  float* ws  = (float*)d_ws;
  float* Sx  = ws;                 // 2048
  float* Sc  = Sx + 2048;          // 2048
  float* TUx = Sc + 2048;          // 131072
  float* TUc = TUx + 131072;       // 131072
  float* OT  = TUc + 131072;       // 131072
  float* WoT = OT + 131072;        // 524288

  hipMemsetAsync(Sx, 0, (size_t)(2 * 2048 + 2 * 131072) * sizeof(float), stream);

  project_token_kernel<<<dim3(16, 8, 4), 256, 0, stream>>>(xc, Wfx, bfx, Wx, bx, Wsl, bsl, temp, TUc, Sc);
  project_token_kernel<<<dim3(16, 8, 4), 256, 0, stream>>>(x,  Wfx, bfx, Wx, bx, Wsl, bsl, temp, TUx, Sx);
  att_kernel<<<dim3(32), dim3(64), 0, stream>>>(TUx, TUc, Sx, Sc, Wq, Wk, Wv, OT);
  wofold_kernel<<<dim3(4, 32), 256, 0, stream>>>(OT, Wo, WoT);
  outx_kernel<<<dim3(512, 4), 256, 0, stream>>>(x, Wx, bx, Wsl, bsl, temp, WoT, bo, out);
}

// Round 2
// 2010.089 us; speedup vs baseline: 1.8943x; 1.3257x over previous
//
#include <hip/hip_runtime.h>
#include <math.h>

constexpr int Bc = 4, Nc = 32768, Cc = 256, Hc = 8, CHc = 64, Mc = 64, INNERc = 512;

typedef _Float16 h8 __attribute__((ext_vector_type(8)));
typedef _Float16 h4 __attribute__((ext_vector_type(4)));
typedef float f32x4 __attribute__((ext_vector_type(4)));

__device__ __forceinline__ void fma4x4(float acc[4][4], const float4 a, const float4 b) {
  acc[0][0] += a.x*b.x; acc[0][1] += a.x*b.y; acc[0][2] += a.x*b.z; acc[0][3] += a.x*b.w;
  acc[1][0] += a.y*b.x; acc[1][1] += a.y*b.y; acc[1][2] += a.y*b.z; acc[1][3] += a.y*b.w;
  acc[2][0] += a.z*b.x; acc[2][1] += a.z*b.y; acc[2][2] += a.z*b.z; acc[2][3] += a.z*b.w;
  acc[3][0] += a.w*b.x; acc[3][1] += a.w*b.y; acc[3][2] += a.w*b.z; acc[3][3] += a.w*b.w;
}

// ============================================================================
// project_token (unchanged from round 1): stage-1 MFMA f16x3, stages 2-4 fp32.
// ============================================================================
__global__ __launch_bounds__(256, 2)
void project_token_kernel(const float* __restrict__ X, const float* __restrict__ Wfx,
                          const float* __restrict__ bfx, const float* __restrict__ Wx,
                          const float* __restrict__ bx, const float* __restrict__ Wsl,
                          const float* __restrict__ bsl, const float* __restrict__ temp,
                          float* __restrict__ TU, float* __restrict__ Ssum)
{
  __shared__ __align__(16) float smem[192 * 68];  // 52,224 B
  float (*FXs)[68] = (float(*)[68])smem;                 // [token][c]
  float (*XMs)[68] = (float(*)[68])(smem + 64*68);       // [c][token]
  float (*Lg)[68]  = (float(*)[68])(smem + 64*68);       // [token][g]
  float (*Ws2)[68] = (float(*)[68])(smem + 128*68);
  _Float16* Xh = (_Float16*)smem;                        // [64][32] f16
  _Float16* Xl = (_Float16*)(smem + 1024);               // [64][32] f16

  const int t = threadIdx.x, tx = t & 15, ty = t >> 4;
  const int chunk = blockIdx.x, h = blockIdx.y, b = blockIdx.z;
  const int bh = b * Hc + h, colBase = h * 64;
  const int w = t >> 6, l = t & 63;
  const int lg = l >> 4, lr = l & 15;
  const int stok = t >> 2, sc8 = (t & 3) << 3;

#pragma unroll
  for (int rep = 0; rep < 4; ++rep) {
    const int v = t + rep * 256, r = v >> 4, c4 = (v & 15) << 2;
    *(float4*)&Ws2[r][c4] = *(const float4*)&Wsl[r * 64 + c4];
  }
  const float invt = 1.0f / fminf(fmaxf(temp[h], 0.1f), 5.0f);
  const float4 bsv = *(const float4*)&bsl[(tx << 2)];
  const float bs_[4] = {bsv.x, bsv.y, bsv.z, bsv.w};

  const float* Wsrc = (w < 2) ? Wfx : Wx;
  const float* bsrc = (w < 2) ? bfx : bx;
  const int wcb = colBase + ((w & 1) << 5);
  h8 wfh[8][2], wfl[8][2];
  float biasv[2];
#pragma unroll
  for (int n = 0; n < 2; ++n) {
    const int col = wcb + (n << 4) + lr;
    biasv[n] = bsrc[col];
#pragma unroll
    for (int ks = 0; ks < 8; ++ks) {
#pragma unroll
      for (int j = 0; j < 8; ++j) {
        const float v = Wsrc[(long)((ks << 5) + (lg << 3) + j) * INNERc + col];
        const _Float16 hi = (_Float16)v;
        wfh[ks][n][j] = hi;
        wfl[ks][n][j] = (_Float16)(v - (float)hi);
      }
    }
  }

  float tuacc[4][4] = {};
  float sreg[4] = {};

  for (int tile = 0; tile < 32; ++tile) {
    const int n0 = chunk * 2048 + tile * 64;
    const long xBase = ((long)b * Nc + n0) * Cc;
    const long xRow = xBase + (long)stok * Cc + sc8;

    f32x4 acc[4][2] = {};
    float4 xa = *(const float4*)&X[xRow];
    float4 xb = *(const float4*)&X[xRow + 4];
#pragma unroll
    for (int ks = 0; ks < 8; ++ks) {
      h8 hv, lv;
      const float va[8] = {xa.x, xa.y, xa.z, xa.w, xb.x, xb.y, xb.z, xb.w};
#pragma unroll
      for (int j = 0; j < 8; ++j) {
        const _Float16 hi = (_Float16)va[j];
        hv[j] = hi;
        lv[j] = (_Float16)(va[j] - (float)hi);
      }
      __syncthreads();
      *(h8*)&Xh[(stok << 5) + sc8] = hv;
      *(h8*)&Xl[(stok << 5) + sc8] = lv;
      __syncthreads();
      if (ks < 7) {
        xa = *(const float4*)&X[xRow + ((ks + 1) << 5)];
        xb = *(const float4*)&X[xRow + ((ks + 1) << 5) + 4];
      }
#pragma unroll
      for (int m = 0; m < 4; ++m) {
        const h8 ah = *(const h8*)&Xh[(((m << 4) + lr) << 5) + (lg << 3)];
        const h8 al = *(const h8*)&Xl[(((m << 4) + lr) << 5) + (lg << 3)];
#pragma unroll
        for (int n = 0; n < 2; ++n) {
          acc[m][n] = __builtin_amdgcn_mfma_f32_16x16x32_f16(ah, wfh[ks][n], acc[m][n], 0, 0, 0);
          acc[m][n] = __builtin_amdgcn_mfma_f32_16x16x32_f16(al, wfh[ks][n], acc[m][n], 0, 0, 0);
          acc[m][n] = __builtin_amdgcn_mfma_f32_16x16x32_f16(ah, wfl[ks][n], acc[m][n], 0, 0, 0);
        }
      }
    }
    __syncthreads();

    if (w < 2) {
#pragma unroll
      for (int m = 0; m < 4; ++m)
#pragma unroll
        for (int n = 0; n < 2; ++n) {
          const int c = ((w & 1) << 5) + (n << 4) + lr;
          const int tokb = (m << 4) + (lg << 2);
#pragma unroll
          for (int i = 0; i < 4; ++i) FXs[tokb + i][c] = acc[m][n][i] + biasv[n];
        }
    } else {
#pragma unroll
      for (int m = 0; m < 4; ++m)
#pragma unroll
        for (int n = 0; n < 2; ++n) {
          const int c = ((w & 1) << 5) + (n << 4) + lr;
          const int tokb = (m << 4) + (lg << 2);
#pragma unroll
          for (int i = 0; i < 4; ++i) XMs[c][tokb + i] = acc[m][n][i] + biasv[n];
        }
    }
    __syncthreads();

    float l2[4][4] = {};
#pragma unroll
    for (int k = 0; k < 64; ++k) {
      const float4 a = *(const float4*)&XMs[k][ty << 2];
      fma4x4(l2, a, *(const float4*)&Ws2[k][tx << 2]);
    }
    float e[4][4];
#pragma unroll
    for (int i = 0; i < 4; ++i) {
      float mx = -1e30f;
#pragma unroll
      for (int j = 0; j < 4; ++j) { l2[i][j] = (l2[i][j] + bs_[j]) * invt; mx = fmaxf(mx, l2[i][j]); }
      for (int d = 1; d < 16; d <<= 1) mx = fmaxf(mx, __shfl_xor(mx, d));
      float s = 0.f;
#pragma unroll
      for (int j = 0; j < 4; ++j) { e[i][j] = __expf(l2[i][j] - mx); s += e[i][j]; }
      for (int d = 1; d < 16; d <<= 1) s += __shfl_xor(s, d);
      const float inv = 1.0f / s;
#pragma unroll
      for (int j = 0; j < 4; ++j) { e[i][j] *= inv; sreg[j] += e[i][j]; }
    }
    __syncthreads();
#pragma unroll
    for (int i = 0; i < 4; ++i)
#pragma unroll
      for (int j = 0; j < 4; ++j) Lg[(ty<<2)+i][(tx<<2)+j] = e[i][j];
    __syncthreads();

#pragma unroll
    for (int k = 0; k < 64; ++k) {
      const float4 a = *(const float4*)&Lg[k][ty << 2];
      fma4x4(tuacc, a, *(const float4*)&FXs[k][tx << 2]);
    }
  }

#pragma unroll
  for (int i = 0; i < 4; ++i)
#pragma unroll
    for (int j = 0; j < 4; ++j)
      atomicAdd(&TU[((long)bh * 64 + (ty<<2)+i) * 64 + (tx<<2)+j], tuacc[i][j]);

  __syncthreads();
#pragma unroll
  for (int j = 0; j < 4; ++j) Ws2[ty][(tx<<2)+j] = sreg[j];
  __syncthreads();
  if (t < 64) {
    float s = 0.f;
    for (int r = 0; r < 16; ++r) s += Ws2[r][t];
    atomicAdd(&Ssum[bh * 64 + t], s);
  }
}

// ============================================================================
// att (unchanged)
// ============================================================================
__global__ __launch_bounds__(64)
void att_kernel(const float* __restrict__ TUx, const float* __restrict__ TUc,
                const float* __restrict__ Sx, const float* __restrict__ Sc,
                const float* __restrict__ Wq, const float* __restrict__ Wk,
                const float* __restrict__ Wv, float* __restrict__ OT)
{
  __shared__ __align__(16) float W[64][68];
  __shared__ __align__(16) float Km[64][68];
  __shared__ __align__(16) float Vm[64][68];
  const int bh = blockIdx.x;
  const int g  = threadIdx.x;
  const float invc = 1.0f / (Sc[bh * 64 + g] + 1e-5f);
  const float invx = 1.0f / (Sx[bh * 64 + g] + 1e-5f);

  for (int i = 0; i < 64; ++i) W[i][g] = Wk[i * 64 + g];
  __syncthreads();
  {
    float4 a[16]; for (int j = 0; j < 16; ++j) a[j] = make_float4(0,0,0,0);
    for (int c = 0; c < 64; ++c) {
      const float tc = TUc[((long)bh * 64 + g) * 64 + c] * invc;
#pragma unroll
      for (int j = 0; j < 16; ++j) {
        const float4 w4 = *(const float4*)&W[c][j << 2];
        a[j].x += tc*w4.x; a[j].y += tc*w4.y; a[j].z += tc*w4.z; a[j].w += tc*w4.w;
      }
    }
    for (int j = 0; j < 16; ++j) *(float4*)&Km[g][j << 2] = a[j];
  }
  __syncthreads();
  for (int i = 0; i < 64; ++i) W[i][g] = Wv[i * 64 + g];
  __syncthreads();
  {
    float4 a[16]; for (int j = 0; j < 16; ++j) a[j] = make_float4(0,0,0,0);
    for (int c = 0; c < 64; ++c) {
      const float tc = TUc[((long)bh * 64 + g) * 64 + c] * invc;
#pragma unroll
      for (int j = 0; j < 16; ++j) {
        const float4 w4 = *(const float4*)&W[c][j << 2];
        a[j].x += tc*w4.x; a[j].y += tc*w4.y; a[j].z += tc*w4.z; a[j].w += tc*w4.w;
      }
    }
    for (int j = 0; j < 16; ++j) *(float4*)&Vm[g][j << 2] = a[j];
  }
  __syncthreads();
  for (int i = 0; i < 64; ++i) W[i][g] = Wq[i * 64 + g];
  __syncthreads();
  float4 qa[16]; for (int j = 0; j < 16; ++j) qa[j] = make_float4(0,0,0,0);
  for (int c = 0; c < 64; ++c) {
    const float tq = TUx[((long)bh * 64 + g) * 64 + c] * invx;
#pragma unroll
    for (int j = 0; j < 16; ++j) {
      const float4 w4 = *(const float4*)&W[c][j << 2];
      qa[j].x += tq*w4.x; qa[j].y += tq*w4.y; qa[j].z += tq*w4.z; qa[j].w += tq*w4.w;
    }
  }
  __syncthreads();
  float (*Am)[68] = W;
  float mx = -1e30f;
  for (int m = 0; m < 64; ++m) {
    float s = 0.f;
#pragma unroll
    for (int j = 0; j < 16; ++j) {
      const float4 k4 = *(const float4*)&Km[m][j << 2];
      s += qa[j].x*k4.x + qa[j].y*k4.y + qa[j].z*k4.z + qa[j].w*k4.w;
    }
    s *= 0.125f;
    Am[m][g] = s;
    mx = fmaxf(mx, s);
  }
  float sum = 0.f;
  for (int m = 0; m < 64; ++m) { const float ev = __expf(Am[m][g] - mx); Am[m][g] = ev; sum += ev; }
  float4 oa[16]; for (int j = 0; j < 16; ++j) oa[j] = make_float4(0,0,0,0);
  for (int m = 0; m < 64; ++m) {
    const float am = Am[m][g];
#pragma unroll
    for (int j = 0; j < 16; ++j) {
      const float4 v4 = *(const float4*)&Vm[m][j << 2];
      oa[j].x += am*v4.x; oa[j].y += am*v4.y; oa[j].z += am*v4.z; oa[j].w += am*v4.w;
    }
  }
  const float so = invx / sum;
#pragma unroll
  for (int j = 0; j < 16; ++j) {
    OT[((long)bh * 64 + ((j<<2)+0)) * 64 + g] = oa[j].x * so;
    OT[((long)bh * 64 + ((j<<2)+1)) * 64 + g] = oa[j].y * so;
    OT[((long)bh * 64 + ((j<<2)+2)) * 64 + g] = oa[j].z * so;
    OT[((long)bh * 64 + ((j<<2)+3)) * 64 + g] = oa[j].w * so;
  }
}

// ============================================================================
// wofold: WoT = OT^T @ Wo per head -> emits TRANSPOSED f16 hi/lo:
//   WoTth/WoTtl[bh][co][g]  (g contiguous -> contiguous MFMA B-frag loads)
// ============================================================================
__global__ __launch_bounds__(256)
void wofold_kernel(const float* __restrict__ OT, const float* __restrict__ Wo,
                   _Float16* __restrict__ WoTth, _Float16* __restrict__ WoTtl)
{
  __shared__ __align__(16) float OTs[64][68];
  __shared__ __align__(16) float Wos[64][68];
  const int t = threadIdx.x, tx = t & 15, ty = t >> 4;
  const int cot = blockIdx.x * 64, bh = blockIdx.y, h = bh & 7;
#pragma unroll
  for (int rep = 0; rep < 4; ++rep) {
    const int v = t + rep * 256, r = v >> 4, q4 = (v & 15) << 2;
    *(float4*)&OTs[r][q4] = *(const float4*)&OT[((long)bh * 64 + r) * 64 + q4];
    *(float4*)&Wos[r][q4] = *(const float4*)&Wo[(long)(h * 64 + r) * 256 + cot + q4];
  }
  __syncthreads();
  float acc[4][4] = {};
#pragma unroll
  for (int k = 0; k < 64; ++k) {
    const float4 a = *(const float4*)&OTs[k][ty << 2];   // g quad
    fma4x4(acc, a, *(const float4*)&Wos[k][tx << 2]);    // co quad
  }
#pragma unroll
  for (int i = 0; i < 4; ++i)
#pragma unroll
    for (int j = 0; j < 4; ++j) {
      const float v = acc[i][j];
      const _Float16 hi = (_Float16)v;
      const long o = ((long)bh * 256 + cot + (tx<<2)+j) * 64 + (ty<<2)+i;
      WoTth[o] = hi;
      WoTtl[o] = (_Float16)(v - (float)hi);
    }
}

// ============================================================================
// wxprep: Wx[256 k][512 col] f32 -> Wxth/Wxtl[512 col][256 k] f16 hi/lo
// (transposed so MFMA B-frags are contiguous 16B loads). Runs once per launch.
// ============================================================================
__global__ __launch_bounds__(256)
void wxprep_kernel(const float* __restrict__ Wx, _Float16* __restrict__ Wxth,
                   _Float16* __restrict__ Wxtl)
{
  __shared__ __align__(16) float Ls[64][68];
  const int t = threadIdx.x;
  const int k0 = blockIdx.x * 64, c0 = blockIdx.y * 64;
  const int r = t >> 4, c4 = (t & 15) << 2;
#pragma unroll
  for (int rr = 0; rr < 4; ++rr)
    *(float4*)&Ls[(rr<<4)+r][c4] = *(const float4*)&Wx[(long)(k0+(rr<<4)+r) * 512 + c0 + c4];
  __syncthreads();
  const int cl = t >> 2, kq = (t & 3) << 4;
  h8 hv0, hv1, lv0, lv1;
#pragma unroll
  for (int kk = 0; kk < 8; ++kk) {
    float v = Ls[kq+kk][cl];
    _Float16 hi = (_Float16)v;
    hv0[kk] = hi; lv0[kk] = (_Float16)(v - (float)hi);
    v = Ls[kq+8+kk][cl];
    hi = (_Float16)v;
    hv1[kk] = hi; lv1[kk] = (_Float16)(v - (float)hi);
  }
  const long o = (long)(c0 + cl) * 256 + k0 + kq;
  *(h8*)&Wxth[o]     = hv0; *(h8*)&Wxth[o + 8] = hv1;
  *(h8*)&Wxtl[o]     = lv0; *(h8*)&Wxtl[o + 8] = lv1;
}

// ============================================================================
// outx (REWRITTEN, MFMA f16x3 everywhere): per (ntile, b) block, 4 waves.
//   X tile (64x256) staged ONCE as f16 hi/lo in LDS, reused across 8 heads.
//   Per head: XM = X@Wx (MFMA, wave w owns cols 16w..16w+15)
//             logits = XM@Wsl (MFMA, Wsl frags in regs), softmax (shfl, f32)
//             out   += sw@WoT (MFMA, wave w owns co 64w..64w+63)
// LDS: Xh/Xl [64][264] f16 (67.6KB) + XMh/XMl(=swh/swl) [64][72] f16 (18.4KB)
//      + Lg [64][68] f32 (17.4KB) = 103.4 KB -> 1 block/CU.
// ============================================================================
__global__ __launch_bounds__(256, 1)
void outx_kernel(const float* __restrict__ X, const _Float16* __restrict__ Wxth,
                 const _Float16* __restrict__ Wxtl, const float* __restrict__ bx,
                 const float* __restrict__ Wsl, const float* __restrict__ bsl,
                 const float* __restrict__ temp,
                 const _Float16* __restrict__ WoTth, const _Float16* __restrict__ WoTtl,
                 const float* __restrict__ bo, float* __restrict__ out)
{
  __shared__ __align__(16) _Float16 Xh[64][264];
  __shared__ __align__(16) _Float16 Xl[64][264];
  __shared__ __align__(16) _Float16 XMh[64][72];   // reused as swh after softmax
  __shared__ __align__(16) _Float16 XMl[64][72];   // reused as swl
  __shared__ __align__(16) float    Lg[64][68];

  const int t = threadIdx.x, tx = t & 15, ty = t >> 4;
  const int w = t >> 6, l = t & 63, lg = l >> 4, lr = l & 15;
  const int n0 = blockIdx.x * 64, b = blockIdx.y;
  const long xBase = ((long)b * Nc + n0) * Cc;

  // ---- stage X tile once: f32 -> f16 hi/lo in LDS (coalesced float4) ----
#pragma unroll
  for (int q = 0; q < 16; ++q) {
    const int row = (q << 2) + w, col = l << 2;
    const float4 v = *(const float4*)&X[xBase + (long)row * 256 + col];
    const float va[4] = {v.x, v.y, v.z, v.w};
    h4 hv, lv;
#pragma unroll
    for (int jj = 0; jj < 4; ++jj) {
      const _Float16 hi = (_Float16)va[jj];
      hv[jj] = hi; lv[jj] = (_Float16)(va[jj] - (float)hi);
    }
    *(h4*)&Xh[row][col] = hv;
    *(h4*)&Xl[row][col] = lv;
  }

  // ---- Wslice B-frags in regs (per wave: g-cols 16w..16w+15), once/block ----
  h8 wslh[2], wsll[2];
#pragma unroll
  for (int ks = 0; ks < 2; ++ks)
#pragma unroll
    for (int j = 0; j < 8; ++j) {
      const float v = Wsl[((ks << 5) + (lg << 3) + j) * 64 + (w << 4) + lr];
      const _Float16 hi = (_Float16)v;
      wslh[ks][j] = hi; wsll[ks][j] = (_Float16)(v - (float)hi);
    }
  const float bslv = bsl[(w << 4) + lr];

  f32x4 oacc[4][4] = {};   // [m(tok)][n(co)] fp32 accumulator, 64 VGPR

  __syncthreads();  // X staging visible

  for (int h = 0; h < Hc; ++h) {
    // ---- Wx B-frags for this head (L2-resident, contiguous 16B loads) ----
    h8 wxh[8], wxl[8];
    const long wxoff = (long)((h << 6) + (w << 4) + lr) * 256 + (lg << 3);
#pragma unroll
    for (int ks = 0; ks < 8; ++ks) {
      wxh[ks] = *(const h8*)&Wxth[wxoff + (ks << 5)];
      wxl[ks] = *(const h8*)&Wxtl[wxoff + (ks << 5)];
    }
    const float bxv = bx[(h << 6) + (w << 4) + lr];
    const float invt = 1.0f / fminf(fmaxf(temp[h], 0.1f), 5.0f);

    // ---- stage 1: XM[64 tok][16-col slice] = X @ Wx_h  (K=256) ----
    f32x4 xma[4] = {};
#pragma unroll
    for (int ks = 0; ks < 8; ++ks) {
#pragma unroll
      for (int m = 0; m < 4; ++m) {
        const h8 ah = *(const h8*)&Xh[(m << 4) + lr][(ks << 5) + (lg << 3)];
        const h8 al = *(const h8*)&Xl[(m << 4) + lr][(ks << 5) + (lg << 3)];
        xma[m] = __builtin_amdgcn_mfma_f32_16x16x32_f16(ah, wxh[ks], xma[m], 0, 0, 0);
        xma[m] = __builtin_amdgcn_mfma_f32_16x16x32_f16(al, wxh[ks], xma[m], 0, 0, 0);
        xma[m] = __builtin_amdgcn_mfma_f32_16x16x32_f16(ah, wxl[ks], xma[m], 0, 0, 0);
      }
    }
    // write XM hi/lo to LDS  (C layout: col=lane&15, row=4*(lane>>4)+reg)
#pragma unroll
    for (int m = 0; m < 4; ++m)
#pragma unroll
      for (int i = 0; i < 4; ++i) {
        const float v = xma[m][i] + bxv;
        const _Float16 hi = (_Float16)v;
        XMh[(m << 4) + (lg << 2) + i][(w << 4) + lr] = hi;
        XMl[(m << 4) + (lg << 2) + i][(w << 4) + lr] = (_Float16)(v - (float)hi);
      }
    __syncthreads();

    // ---- WoT B-frags for this head (issue early to hide L2 latency) ----
    const int bh = (b << 3) + h;
    h8 wth[4][2], wtl[4][2];
#pragma unroll
    for (int n = 0; n < 4; ++n)
#pragma unroll
      for (int ks = 0; ks < 2; ++ks) {
        const long o = ((long)(bh << 8) + (w << 6) + (n << 4) + lr) * 64 + (ks << 5) + (lg << 3);
        wth[n][ks] = *(const h8*)&WoTth[o];
        wtl[n][ks] = *(const h8*)&WoTtl[o];
      }

    // ---- stage 2: logits = XM @ Wsl  (K=64) ----
    f32x4 lga[4] = {};
#pragma unroll
    for (int ks = 0; ks < 2; ++ks)
#pragma unroll
      for (int m = 0; m < 4; ++m) {
        const h8 ah = *(const h8*)&XMh[(m << 4) + lr][(ks << 5) + (lg << 3)];
        const h8 al = *(const h8*)&XMl[(m << 4) + lr][(ks << 5) + (lg << 3)];
        lga[m] = __builtin_amdgcn_mfma_f32_16x16x32_f16(ah, wslh[ks], lga[m], 0, 0, 0);
        lga[m] = __builtin_amdgcn_mfma_f32_16x16x32_f16(al, wslh[ks], lga[m], 0, 0, 0);
        lga[m] = __builtin_amdgcn_mfma_f32_16x16x32_f16(ah, wsll[ks], lga[m], 0, 0, 0);
      }
#pragma unroll
    for (int m = 0; m < 4; ++m)
#pragma unroll
      for (int i = 0; i < 4; ++i)
        Lg[(m << 4) + (lg << 2) + i][(w << 4) + lr] = (lga[m][i] + bslv) * invt;
    __syncthreads();   // also orders all XM frag reads before sw overlay below

    // ---- stage 3: softmax over g (16-lane shfl groups, unchanged math) ----
    float e[4][4];
#pragma unroll
    for (int i = 0; i < 4; ++i) {
      const float4 lv4 = *(const float4*)&Lg[(ty << 2) + i][tx << 2];
      const float lrow[4] = {lv4.x, lv4.y, lv4.z, lv4.w};
      float mx = fmaxf(fmaxf(lrow[0], lrow[1]), fmaxf(lrow[2], lrow[3]));
      for (int d = 1; d < 16; d <<= 1) mx = fmaxf(mx, __shfl_xor(mx, d));
      float s = 0.f;
#pragma unroll
      for (int j = 0; j < 4; ++j) { e[i][j] = __expf(lrow[j] - mx); s += e[i][j]; }
      for (int d = 1; d < 16; d <<= 1) s += __shfl_xor(s, d);
      const float inv = 1.0f / s;
#pragma unroll
      for (int j = 0; j < 4; ++j) e[i][j] *= inv;
    }
    // write sw hi/lo into the (dead) XM buffers
#pragma unroll
    for (int i = 0; i < 4; ++i)
#pragma unroll
      for (int j = 0; j < 4; ++j) {
        const _Float16 hi = (_Float16)e[i][j];
        XMh[(ty << 2) + i][(tx << 2) + j] = hi;
        XMl[(ty << 2) + i][(tx << 2) + j] = (_Float16)(e[i][j] - (float)hi);
      }
    __syncthreads();

    // ---- stage 4: out += sw @ WoT  (K=64, wave owns 64 co) ----
#pragma unroll
    for (int ks = 0; ks < 2; ++ks)
#pragma unroll
      for (int m = 0; m < 4; ++m) {
        const h8 ah = *(const h8*)&XMh[(m << 4) + lr][(ks << 5) + (lg << 3)];
        const h8 al = *(const h8*)&XMl[(m << 4) + lr][(ks << 5) + (lg << 3)];
#pragma unroll
        for (int n = 0; n < 4; ++n) {
          oacc[m][n] = __builtin_amdgcn_mfma_f32_16x16x32_f16(ah, wth[n][ks], oacc[m][n], 0, 0, 0);
          oacc[m][n] = __builtin_amdgcn_mfma_f32_16x16x32_f16(al, wth[n][ks], oacc[m][n], 0, 0, 0);
          oacc[m][n] = __builtin_amdgcn_mfma_f32_16x16x32_f16(ah, wtl[n][ks], oacc[m][n], 0, 0, 0);
        }
      }
    __syncthreads();  // sw reads done before next head's XM writes
  }

  // ---- epilogue: out[tok][co] = oacc + bo ----
#pragma unroll
  for (int n = 0; n < 4; ++n) {
    const float bov = bo[(w << 6) + (n << 4) + lr];
#pragma unroll
    for (int m = 0; m < 4; ++m)
#pragma unroll
      for (int i = 0; i < 4; ++i)
        out[((long)b * Nc + n0 + (m << 4) + (lg << 2) + i) * 256 + (w << 6) + (n << 4) + lr]
            = oacc[m][n][i] + bov;
  }
}

extern "C" void kernel_launch(void* const* d_in, const int* in_sizes, int n_in,
                              void* d_out, int out_size, void* d_ws, size_t ws_size,
                              hipStream_t stream)
{
  (void)in_sizes; (void)n_in; (void)out_size; (void)ws_size;
  const float* x    = (const float*)d_in[0];
  const float* xc   = (const float*)d_in[1];
  const float* Wfx  = (const float*)d_in[2];
  const float* bfx  = (const float*)d_in[3];
  const float* Wx   = (const float*)d_in[4];
  const float* bx   = (const float*)d_in[5];
  const float* Wsl  = (const float*)d_in[6];
  const float* bsl  = (const float*)d_in[7];
  const float* temp = (const float*)d_in[8];
  const float* Wq   = (const float*)d_in[9];
  const float* Wk   = (const float*)d_in[10];
  const float* Wv   = (const float*)d_in[11];
  const float* Wo   = (const float*)d_in[12];
  const float* bo   = (const float*)d_in[13];
  float* out = (float*)d_out;

  // workspace layout (floats unless noted): total 1,052,672 f32 = 4.21 MB
  float* ws  = (float*)d_ws;
  float* Sx  = ws;                 // 2048
  float* Sc  = Sx + 2048;          // 2048
  float* TUx = Sc + 2048;          // 131072
  float* TUc = TUx + 131072;       // 131072
  float* OT  = TUc + 131072;       // 131072
  _Float16* WoTth = (_Float16*)(OT + 131072);   // 524288 f16 [bh][co][g]
  _Float16* WoTtl = WoTth + 524288;             // 524288 f16
  _Float16* Wxth  = WoTtl + 524288;             // 131072 f16 [col][k]
  _Float16* Wxtl  = Wxth + 131072;              // 131072 f16

  hipMemsetAsync(Sx, 0, (size_t)(2 * 2048 + 2 * 131072) * sizeof(float), stream);

  wxprep_kernel<<<dim3(4, 8), 256, 0, stream>>>(Wx, Wxth, Wxtl);
  project_token_kernel<<<dim3(16, 8, 4), 256, 0, stream>>>(xc, Wfx, bfx, Wx, bx, Wsl, bsl, temp, TUc, Sc);
  project_token_kernel<<<dim3(16, 8, 4), 256, 0, stream>>>(x,  Wfx, bfx, Wx, bx, Wsl, bsl, temp, TUx, Sx);
  att_kernel<<<dim3(32), dim3(64), 0, stream>>>(TUx, TUc, Sx, Sc, Wq, Wk, Wv, OT);
  wofold_kernel<<<dim3(4, 32), 256, 0, stream>>>(OT, Wo, WoTth, WoTtl);
  outx_kernel<<<dim3(512, 4), 256, 0, stream>>>(x, Wxth, Wxtl, bx, Wsl, bsl, temp, WoTth, WoTtl, bo, out);
}

// Round 3
// 1551.409 us; speedup vs baseline: 2.4543x; 1.2957x over previous
//
#include <hip/hip_runtime.h>
#include <math.h>

constexpr int Bc = 4, Nc = 32768, Cc = 256, Hc = 8, CHc = 64, Mc = 64, INNERc = 512;

typedef _Float16 h8 __attribute__((ext_vector_type(8)));
typedef _Float16 h4 __attribute__((ext_vector_type(4)));
typedef float f32x4 __attribute__((ext_vector_type(4)));

__device__ __forceinline__ void fma4x4(float acc[4][4], const float4 a, const float4 b) {
  acc[0][0] += a.x*b.x; acc[0][1] += a.x*b.y; acc[0][2] += a.x*b.z; acc[0][3] += a.x*b.w;
  acc[1][0] += a.y*b.x; acc[1][1] += a.y*b.y; acc[1][2] += a.y*b.z; acc[1][3] += a.y*b.w;
  acc[2][0] += a.z*b.x; acc[2][1] += a.z*b.y; acc[2][2] += a.z*b.z; acc[2][3] += a.z*b.w;
  acc[3][0] += a.w*b.x; acc[3][1] += a.w*b.y; acc[3][2] += a.w*b.z; acc[3][3] += a.w*b.w;
}

// ============================================================================
// project_token (REWRITTEN, full MFMA f16x3): merged x/xc via blockIdx.z.
// Per (chunk, h, bz) block, 4 waves, 32 token-tiles:
//  stage 1: FX|XM = X @ [Wfx|Wx]  (MFMA; W frags in 128 VGPR, X staged per
//           32-K chunk f16 hi/lo, DOUBLE-BUFFERED -> 1 barrier/kstep; rows
//           padded to 40 f16 -> conflict-free frag reads)
//  stage 2: logits = XM @ Wsl (MFMA; Wsl frags in 32 VGPR; wave w owns
//           tokens 16w..16w+15, all 64 g)
//  stage 3: softmax over g (f32, shfl over 16-lane groups)
//  stage 4: TU[g][c] += sw^T @ FX (MFMA; wave w owns g 16w..16w+15;
//           A = swT[g][tok] overlay on XM buffers, B = FXT[c][tok])
// LDS: Xst 2x2x[64][40] f16 (20.5K) + FXT 2x[64][72] (18.4K)
//      + XMT/swT 2x[64][72] (18.4K) + Sred [16][64] f32 (4K) = 61,440 B
// ============================================================================
__global__ __launch_bounds__(256, 2)
void project_token_kernel(const float* __restrict__ Xx, const float* __restrict__ Xc,
                          const float* __restrict__ Wfx, const float* __restrict__ bfx,
                          const float* __restrict__ Wx, const float* __restrict__ bx,
                          const float* __restrict__ Wsl, const float* __restrict__ bsl,
                          const float* __restrict__ temp,
                          float* __restrict__ TUx, float* __restrict__ TUc,
                          float* __restrict__ Ssx, float* __restrict__ Ssc)
{
  __shared__ __align__(16) _Float16 Xst[2][2][64][40];  // [dbuf][hi/lo][tok][k]
  __shared__ __align__(16) _Float16 FXT[2][64][72];     // [hi/lo][c][tok]
  __shared__ __align__(16) _Float16 XMT[2][64][72];     // [hi/lo][tok][c] -> swT[hi/lo][g][tok]
  __shared__ __align__(16) float Sred[16][64];

  const int t = threadIdx.x;
  const int chunk = blockIdx.x, h = blockIdx.y, bz = blockIdx.z;
  const int b = bz & 3;
  const float* X = (bz < 4) ? Xx : Xc;
  float* TU   = (bz < 4) ? TUx : TUc;
  float* Ssum = (bz < 4) ? Ssx : Ssc;
  const int bh = b * Hc + h, colBase = h * 64;
  const int w = t >> 6, l = t & 63, lg = l >> 4, lr = l & 15;
  const int stok = t >> 2, sc8 = (t & 3) << 3;

  const float invt = 1.0f / fminf(fmaxf(temp[h], 0.1f), 5.0f);

  // ---- stage-1 W frags: waves 0,1 -> Wfx cols, waves 2,3 -> Wx cols ----
  const float* Wsrc = (w < 2) ? Wfx : Wx;
  const float* bsrc = (w < 2) ? bfx : bx;
  const int wcb = colBase + ((w & 1) << 5);
  h8 wfh[8][2], wfl[8][2];
  float biasv[2];
#pragma unroll
  for (int n = 0; n < 2; ++n) {
    const int col = wcb + (n << 4) + lr;
    biasv[n] = bsrc[col];
#pragma unroll
    for (int ks = 0; ks < 8; ++ks)
#pragma unroll
      for (int j = 0; j < 8; ++j) {
        const float v = Wsrc[(long)((ks << 5) + (lg << 3) + j) * INNERc + col];
        const _Float16 hi = (_Float16)v;
        wfh[ks][n][j] = hi;
        wfl[ks][n][j] = (_Float16)(v - (float)hi);
      }
  }
  // ---- Wsl frags (all 64 g per wave) ----
  h8 wslh[2][4], wsll[2][4];
#pragma unroll
  for (int ks = 0; ks < 2; ++ks)
#pragma unroll
    for (int n = 0; n < 4; ++n)
#pragma unroll
      for (int j = 0; j < 8; ++j) {
        const float v = Wsl[((ks << 5) + (lg << 3) + j) * 64 + (n << 4) + lr];
        const _Float16 hi = (_Float16)v;
        wslh[ks][n][j] = hi;
        wsll[ks][n][j] = (_Float16)(v - (float)hi);
      }
  float bs_n[4];
#pragma unroll
  for (int n = 0; n < 4; ++n) bs_n[n] = bsl[(n << 4) + lr];

  f32x4 tuacc[4] = {};
  float sregn[4] = {};

  for (int tile = 0; tile < 32; ++tile) {
    const int n0 = chunk * 2048 + tile * 64;
    const long xRow = ((long)(b * Nc + n0 + stok)) * Cc + sc8;

    // ---- stage 1: double-buffered staging, 1 barrier per kstep ----
    f32x4 acc[4][2] = {};
    {
      const float4 xa = *(const float4*)&X[xRow];
      const float4 xb = *(const float4*)&X[xRow + 4];
      const float va[8] = {xa.x, xa.y, xa.z, xa.w, xb.x, xb.y, xb.z, xb.w};
      h8 hv, lv;
#pragma unroll
      for (int j = 0; j < 8; ++j) {
        const _Float16 hi = (_Float16)va[j];
        hv[j] = hi; lv[j] = (_Float16)(va[j] - (float)hi);
      }
      *(h8*)&Xst[0][0][stok][sc8] = hv;
      *(h8*)&Xst[0][1][stok][sc8] = lv;
    }
#pragma unroll
    for (int ks = 0; ks < 8; ++ks) {
      const int cb = ks & 1;
      __syncthreads();                 // buf cb ready; 2-iter-old reads done
      float4 xa, xb;
      if (ks < 7) {                    // issue next-chunk loads early
        xa = *(const float4*)&X[xRow + ((ks + 1) << 5)];
        xb = *(const float4*)&X[xRow + ((ks + 1) << 5) + 4];
      }
#pragma unroll
      for (int m = 0; m < 4; ++m) {
        const h8 ah = *(const h8*)&Xst[cb][0][(m << 4) + lr][lg << 3];
        const h8 al = *(const h8*)&Xst[cb][1][(m << 4) + lr][lg << 3];
#pragma unroll
        for (int n = 0; n < 2; ++n) {
          acc[m][n] = __builtin_amdgcn_mfma_f32_16x16x32_f16(ah, wfh[ks][n], acc[m][n], 0, 0, 0);
          acc[m][n] = __builtin_amdgcn_mfma_f32_16x16x32_f16(al, wfh[ks][n], acc[m][n], 0, 0, 0);
          acc[m][n] = __builtin_amdgcn_mfma_f32_16x16x32_f16(ah, wfl[ks][n], acc[m][n], 0, 0, 0);
        }
      }
      if (ks < 7) {                    // convert + write next buffer
        const float va[8] = {xa.x, xa.y, xa.z, xa.w, xb.x, xb.y, xb.z, xb.w};
        h8 hv, lv;
#pragma unroll
        for (int j = 0; j < 8; ++j) {
          const _Float16 hi = (_Float16)va[j];
          hv[j] = hi; lv[j] = (_Float16)(va[j] - (float)hi);
        }
        *(h8*)&Xst[cb ^ 1][0][stok][sc8] = hv;
        *(h8*)&Xst[cb ^ 1][1][stok][sc8] = lv;
      }
    }

    // ---- epilogue: FX (waves 0,1) / XM (waves 2,3) as f16 hi/lo ----
    // C layout: col = lane&15, row = 4*(lane>>4)+reg  [HW-verified]
    if (w < 2) {
#pragma unroll
      for (int m = 0; m < 4; ++m)
#pragma unroll
        for (int n = 0; n < 2; ++n) {
          const int c = ((w & 1) << 5) + (n << 4) + lr;
          const int tokb = (m << 4) + (lg << 2);
          h4 hv, lv;
#pragma unroll
          for (int i = 0; i < 4; ++i) {
            const float v = acc[m][n][i] + biasv[n];
            const _Float16 hi = (_Float16)v;
            hv[i] = hi; lv[i] = (_Float16)(v - (float)hi);
          }
          *(h4*)&FXT[0][c][tokb] = hv;
          *(h4*)&FXT[1][c][tokb] = lv;
        }
    } else {
#pragma unroll
      for (int m = 0; m < 4; ++m)
#pragma unroll
        for (int n = 0; n < 2; ++n) {
          const int c = ((w & 1) << 5) + (n << 4) + lr;
#pragma unroll
          for (int i = 0; i < 4; ++i) {
            const float v = acc[m][n][i] + biasv[n];
            const _Float16 hi = (_Float16)v;
            XMT[0][(m << 4) + (lg << 2) + i][c] = hi;
            XMT[1][(m << 4) + (lg << 2) + i][c] = (_Float16)(v - (float)hi);
          }
        }
    }
    __syncthreads();

    // ---- stage 2: logits = XM @ Wsl (wave w: tokens 16w..16w+15) ----
    f32x4 lga[4] = {};
#pragma unroll
    for (int ks = 0; ks < 2; ++ks) {
      const h8 ah = *(const h8*)&XMT[0][(w << 4) + lr][(ks << 5) + (lg << 3)];
      const h8 al = *(const h8*)&XMT[1][(w << 4) + lr][(ks << 5) + (lg << 3)];
#pragma unroll
      for (int n = 0; n < 4; ++n) {
        lga[n] = __builtin_amdgcn_mfma_f32_16x16x32_f16(ah, wslh[ks][n], lga[n], 0, 0, 0);
        lga[n] = __builtin_amdgcn_mfma_f32_16x16x32_f16(al, wslh[ks][n], lga[n], 0, 0, 0);
        lga[n] = __builtin_amdgcn_mfma_f32_16x16x32_f16(ah, wsll[ks][n], lga[n], 0, 0, 0);
      }
    }
    __syncthreads();   // XMT reads done before swT overlay writes

    // ---- stage 3: softmax over g; token = 16w+4lg+i, g = 16n+lr ----
    float sw[4][4];    // [n][i]
#pragma unroll
    for (int i = 0; i < 4; ++i) {
      float mx = -1e30f;
#pragma unroll
      for (int n = 0; n < 4; ++n) {
        const float lv = (lga[n][i] + bs_n[n]) * invt;
        sw[n][i] = lv; mx = fmaxf(mx, lv);
      }
      for (int d = 1; d < 16; d <<= 1) mx = fmaxf(mx, __shfl_xor(mx, d));
      float s = 0.f;
#pragma unroll
      for (int n = 0; n < 4; ++n) { sw[n][i] = __expf(sw[n][i] - mx); s += sw[n][i]; }
      for (int d = 1; d < 16; d <<= 1) s += __shfl_xor(s, d);
      const float inv = 1.0f / s;
#pragma unroll
      for (int n = 0; n < 4; ++n) { sw[n][i] *= inv; sregn[n] += sw[n][i]; }
    }
    // write swT[g][tok] hi/lo into dead XM buffers (h4: 4 contiguous tok)
#pragma unroll
    for (int n = 0; n < 4; ++n) {
      h4 hv, lv;
#pragma unroll
      for (int i = 0; i < 4; ++i) {
        const _Float16 hi = (_Float16)sw[n][i];
        hv[i] = hi; lv[i] = (_Float16)(sw[n][i] - (float)hi);
      }
      *(h4*)&XMT[0][(n << 4) + lr][(w << 4) + (lg << 2)] = hv;
      *(h4*)&XMT[1][(n << 4) + lr][(w << 4) + (lg << 2)] = lv;
    }
    __syncthreads();

    // ---- stage 4: TU[g][c] += sw^T @ FX (wave w: g rows 16w..16w+15) ----
#pragma unroll
    for (int ks = 0; ks < 2; ++ks) {
      const h8 ah = *(const h8*)&XMT[0][(w << 4) + lr][(ks << 5) + (lg << 3)];
      const h8 al = *(const h8*)&XMT[1][(w << 4) + lr][(ks << 5) + (lg << 3)];
#pragma unroll
      for (int n = 0; n < 4; ++n) {
        const h8 bhv = *(const h8*)&FXT[0][(n << 4) + lr][(ks << 5) + (lg << 3)];
        const h8 blv = *(const h8*)&FXT[1][(n << 4) + lr][(ks << 5) + (lg << 3)];
        tuacc[n] = __builtin_amdgcn_mfma_f32_16x16x32_f16(ah, bhv, tuacc[n], 0, 0, 0);
        tuacc[n] = __builtin_amdgcn_mfma_f32_16x16x32_f16(al, bhv, tuacc[n], 0, 0, 0);
        tuacc[n] = __builtin_amdgcn_mfma_f32_16x16x32_f16(ah, blv, tuacc[n], 0, 0, 0);
      }
    }
    // no trailing barrier: next tile's stage-1 barriers cover the hazards
  }

  // ---- TU atomics: g = 16w+4lg+i, c = 16n+lr ----
#pragma unroll
  for (int n = 0; n < 4; ++n)
#pragma unroll
    for (int i = 0; i < 4; ++i)
      atomicAdd(&TU[((long)bh * 64 + (w << 4) + (lg << 2) + i) * 64 + (n << 4) + lr],
                tuacc[n][i]);

  // ---- Ssum reduce ----
  __syncthreads();
#pragma unroll
  for (int n = 0; n < 4; ++n) Sred[(w << 2) + lg][(n << 4) + lr] = sregn[n];
  __syncthreads();
  if (t < 64) {
    float s = 0.f;
    for (int r = 0; r < 16; ++r) s += Sred[r][t];
    atomicAdd(&Ssum[bh * 64 + t], s);
  }
}

// ============================================================================
// att (unchanged)
// ============================================================================
__global__ __launch_bounds__(64)
void att_kernel(const float* __restrict__ TUx, const float* __restrict__ TUc,
                const float* __restrict__ Sx, const float* __restrict__ Sc,
                const float* __restrict__ Wq, const float* __restrict__ Wk,
                const float* __restrict__ Wv, float* __restrict__ OT)
{
  __shared__ __align__(16) float W[64][68];
  __shared__ __align__(16) float Km[64][68];
  __shared__ __align__(16) float Vm[64][68];
  const int bh = blockIdx.x;
  const int g  = threadIdx.x;
  const float invc = 1.0f / (Sc[bh * 64 + g] + 1e-5f);
  const float invx = 1.0f / (Sx[bh * 64 + g] + 1e-5f);

  for (int i = 0; i < 64; ++i) W[i][g] = Wk[i * 64 + g];
  __syncthreads();
  {
    float4 a[16]; for (int j = 0; j < 16; ++j) a[j] = make_float4(0,0,0,0);
    for (int c = 0; c < 64; ++c) {
      const float tc = TUc[((long)bh * 64 + g) * 64 + c] * invc;
#pragma unroll
      for (int j = 0; j < 16; ++j) {
        const float4 w4 = *(const float4*)&W[c][j << 2];
        a[j].x += tc*w4.x; a[j].y += tc*w4.y; a[j].z += tc*w4.z; a[j].w += tc*w4.w;
      }
    }
    for (int j = 0; j < 16; ++j) *(float4*)&Km[g][j << 2] = a[j];
  }
  __syncthreads();
  for (int i = 0; i < 64; ++i) W[i][g] = Wv[i * 64 + g];
  __syncthreads();
  {
    float4 a[16]; for (int j = 0; j < 16; ++j) a[j] = make_float4(0,0,0,0);
    for (int c = 0; c < 64; ++c) {
      const float tc = TUc[((long)bh * 64 + g) * 64 + c] * invc;
#pragma unroll
      for (int j = 0; j < 16; ++j) {
        const float4 w4 = *(const float4*)&W[c][j << 2];
        a[j].x += tc*w4.x; a[j].y += tc*w4.y; a[j].z += tc*w4.z; a[j].w += tc*w4.w;
      }
    }
    for (int j = 0; j < 16; ++j) *(float4*)&Vm[g][j << 2] = a[j];
  }
  __syncthreads();
  for (int i = 0; i < 64; ++i) W[i][g] = Wq[i * 64 + g];
  __syncthreads();
  float4 qa[16]; for (int j = 0; j < 16; ++j) qa[j] = make_float4(0,0,0,0);
  for (int c = 0; c < 64; ++c) {
    const float tq = TUx[((long)bh * 64 + g) * 64 + c] * invx;
#pragma unroll
    for (int j = 0; j < 16; ++j) {
      const float4 w4 = *(const float4*)&W[c][j << 2];
      qa[j].x += tq*w4.x; qa[j].y += tq*w4.y; qa[j].z += tq*w4.z; qa[j].w += tq*w4.w;
    }
  }
  __syncthreads();
  float (*Am)[68] = W;
  float mx = -1e30f;
  for (int m = 0; m < 64; ++m) {
    float s = 0.f;
#pragma unroll
    for (int j = 0; j < 16; ++j) {
      const float4 k4 = *(const float4*)&Km[m][j << 2];
      s += qa[j].x*k4.x + qa[j].y*k4.y + qa[j].z*k4.z + qa[j].w*k4.w;
    }
    s *= 0.125f;
    Am[m][g] = s;
    mx = fmaxf(mx, s);
  }
  float sum = 0.f;
  for (int m = 0; m < 64; ++m) { const float ev = __expf(Am[m][g] - mx); Am[m][g] = ev; sum += ev; }
  float4 oa[16]; for (int j = 0; j < 16; ++j) oa[j] = make_float4(0,0,0,0);
  for (int m = 0; m < 64; ++m) {
    const float am = Am[m][g];
#pragma unroll
    for (int j = 0; j < 16; ++j) {
      const float4 v4 = *(const float4*)&Vm[m][j << 2];
      oa[j].x += am*v4.x; oa[j].y += am*v4.y; oa[j].z += am*v4.z; oa[j].w += am*v4.w;
    }
  }
  const float so = invx / sum;
#pragma unroll
  for (int j = 0; j < 16; ++j) {
    OT[((long)bh * 64 + ((j<<2)+0)) * 64 + g] = oa[j].x * so;
    OT[((long)bh * 64 + ((j<<2)+1)) * 64 + g] = oa[j].y * so;
    OT[((long)bh * 64 + ((j<<2)+2)) * 64 + g] = oa[j].z * so;
    OT[((long)bh * 64 + ((j<<2)+3)) * 64 + g] = oa[j].w * so;
  }
}

// ============================================================================
// wofold (unchanged): emits WoT transposed f16 hi/lo [bh][co][g]
// ============================================================================
__global__ __launch_bounds__(256)
void wofold_kernel(const float* __restrict__ OT, const float* __restrict__ Wo,
                   _Float16* __restrict__ WoTth, _Float16* __restrict__ WoTtl)
{
  __shared__ __align__(16) float OTs[64][68];
  __shared__ __align__(16) float Wos[64][68];
  const int t = threadIdx.x, tx = t & 15, ty = t >> 4;
  const int cot = blockIdx.x * 64, bh = blockIdx.y, h = bh & 7;
#pragma unroll
  for (int rep = 0; rep < 4; ++rep) {
    const int v = t + rep * 256, r = v >> 4, q4 = (v & 15) << 2;
    *(float4*)&OTs[r][q4] = *(const float4*)&OT[((long)bh * 64 + r) * 64 + q4];
    *(float4*)&Wos[r][q4] = *(const float4*)&Wo[(long)(h * 64 + r) * 256 + cot + q4];
  }
  __syncthreads();
  float acc[4][4] = {};
#pragma unroll
  for (int k = 0; k < 64; ++k) {
    const float4 a = *(const float4*)&OTs[k][ty << 2];
    fma4x4(acc, a, *(const float4*)&Wos[k][tx << 2]);
  }
#pragma unroll
  for (int i = 0; i < 4; ++i)
#pragma unroll
    for (int j = 0; j < 4; ++j) {
      const float v = acc[i][j];
      const _Float16 hi = (_Float16)v;
      const long o = ((long)bh * 256 + cot + (tx<<2)+j) * 64 + (ty<<2)+i;
      WoTth[o] = hi;
      WoTtl[o] = (_Float16)(v - (float)hi);
    }
}

// ============================================================================
// wxprep (unchanged): Wx -> Wxth/Wxtl[col][k] f16 hi/lo
// ============================================================================
__global__ __launch_bounds__(256)
void wxprep_kernel(const float* __restrict__ Wx, _Float16* __restrict__ Wxth,
                   _Float16* __restrict__ Wxtl)
{
  __shared__ __align__(16) float Ls[64][68];
  const int t = threadIdx.x;
  const int k0 = blockIdx.x * 64, c0 = blockIdx.y * 64;
  const int r = t >> 4, c4 = (t & 15) << 2;
#pragma unroll
  for (int rr = 0; rr < 4; ++rr)
    *(float4*)&Ls[(rr<<4)+r][c4] = *(const float4*)&Wx[(long)(k0+(rr<<4)+r) * 512 + c0 + c4];
  __syncthreads();
  const int cl = t >> 2, kq = (t & 3) << 4;
  h8 hv0, hv1, lv0, lv1;
#pragma unroll
  for (int kk = 0; kk < 8; ++kk) {
    float v = Ls[kq+kk][cl];
    _Float16 hi = (_Float16)v;
    hv0[kk] = hi; lv0[kk] = (_Float16)(v - (float)hi);
    v = Ls[kq+8+kk][cl];
    hi = (_Float16)v;
    hv1[kk] = hi; lv1[kk] = (_Float16)(v - (float)hi);
  }
  const long o = (long)(c0 + cl) * 256 + k0 + kq;
  *(h8*)&Wxth[o]     = hv0; *(h8*)&Wxth[o + 8] = hv1;
  *(h8*)&Wxtl[o]     = lv0; *(h8*)&Wxtl[o + 8] = lv1;
}

// ============================================================================
// outx (unchanged from round 2)
// ============================================================================
__global__ __launch_bounds__(256, 1)
void outx_kernel(const float* __restrict__ X, const _Float16* __restrict__ Wxth,
                 const _Float16* __restrict__ Wxtl, const float* __restrict__ bx,
                 const float* __restrict__ Wsl, const float* __restrict__ bsl,
                 const float* __restrict__ temp,
                 const _Float16* __restrict__ WoTth, const _Float16* __restrict__ WoTtl,
                 const float* __restrict__ bo, float* __restrict__ out)
{
  __shared__ __align__(16) _Float16 Xh[64][264];
  __shared__ __align__(16) _Float16 Xl[64][264];
  __shared__ __align__(16) _Float16 XMh[64][72];
  __shared__ __align__(16) _Float16 XMl[64][72];
  __shared__ __align__(16) float    Lg[64][68];

  const int t = threadIdx.x, tx = t & 15, ty = t >> 4;
  const int w = t >> 6, l = t & 63, lg = l >> 4, lr = l & 15;
  const int n0 = blockIdx.x * 64, b = blockIdx.y;
  const long xBase = ((long)b * Nc + n0) * Cc;

#pragma unroll
  for (int q = 0; q < 16; ++q) {
    const int row = (q << 2) + w, col = l << 2;
    const float4 v = *(const float4*)&X[xBase + (long)row * 256 + col];
    const float va[4] = {v.x, v.y, v.z, v.w};
    h4 hv, lv;
#pragma unroll
    for (int jj = 0; jj < 4; ++jj) {
      const _Float16 hi = (_Float16)va[jj];
      hv[jj] = hi; lv[jj] = (_Float16)(va[jj] - (float)hi);
    }
    *(h4*)&Xh[row][col] = hv;
    *(h4*)&Xl[row][col] = lv;
  }

  h8 wslh[2], wsll[2];
#pragma unroll
  for (int ks = 0; ks < 2; ++ks)
#pragma unroll
    for (int j = 0; j < 8; ++j) {
      const float v = Wsl[((ks << 5) + (lg << 3) + j) * 64 + (w << 4) + lr];
      const _Float16 hi = (_Float16)v;
      wslh[ks][j] = hi; wsll[ks][j] = (_Float16)(v - (float)hi);
    }
  const float bslv = bsl[(w << 4) + lr];

  f32x4 oacc[4][4] = {};

  __syncthreads();

  for (int h = 0; h < Hc; ++h) {
    h8 wxh[8], wxl[8];
    const long wxoff = (long)((h << 6) + (w << 4) + lr) * 256 + (lg << 3);
#pragma unroll
    for (int ks = 0; ks < 8; ++ks) {
      wxh[ks] = *(const h8*)&Wxth[wxoff + (ks << 5)];
      wxl[ks] = *(const h8*)&Wxtl[wxoff + (ks << 5)];
    }
    const float bxv = bx[(h << 6) + (w << 4) + lr];
    const float invt = 1.0f / fminf(fmaxf(temp[h], 0.1f), 5.0f);

    f32x4 xma[4] = {};
#pragma unroll
    for (int ks = 0; ks < 8; ++ks) {
#pragma unroll
      for (int m = 0; m < 4; ++m) {
        const h8 ah = *(const h8*)&Xh[(m << 4) + lr][(ks << 5) + (lg << 3)];
        const h8 al = *(const h8*)&Xl[(m << 4) + lr][(ks << 5) + (lg << 3)];
        xma[m] = __builtin_amdgcn_mfma_f32_16x16x32_f16(ah, wxh[ks], xma[m], 0, 0, 0);
        xma[m] = __builtin_amdgcn_mfma_f32_16x16x32_f16(al, wxh[ks], xma[m], 0, 0, 0);
        xma[m] = __builtin_amdgcn_mfma_f32_16x16x32_f16(ah, wxl[ks], xma[m], 0, 0, 0);
      }
    }
#pragma unroll
    for (int m = 0; m < 4; ++m)
#pragma unroll
      for (int i = 0; i < 4; ++i) {
        const float v = xma[m][i] + bxv;
        const _Float16 hi = (_Float16)v;
        XMh[(m << 4) + (lg << 2) + i][(w << 4) + lr] = hi;
        XMl[(m << 4) + (lg << 2) + i][(w << 4) + lr] = (_Float16)(v - (float)hi);
      }
    __syncthreads();

    const int bh = (b << 3) + h;
    h8 wth[4][2], wtl[4][2];
#pragma unroll
    for (int n = 0; n < 4; ++n)
#pragma unroll
      for (int ks = 0; ks < 2; ++ks) {
        const long o = ((long)(bh << 8) + (w << 6) + (n << 4) + lr) * 64 + (ks << 5) + (lg << 3);
        wth[n][ks] = *(const h8*)&WoTth[o];
        wtl[n][ks] = *(const h8*)&WoTtl[o];
      }

    f32x4 lga[4] = {};
#pragma unroll
    for (int ks = 0; ks < 2; ++ks)
#pragma unroll
      for (int m = 0; m < 4; ++m) {
        const h8 ah = *(const h8*)&XMh[(m << 4) + lr][(ks << 5) + (lg << 3)];
        const h8 al = *(const h8*)&XMl[(m << 4) + lr][(ks << 5) + (lg << 3)];
        lga[m] = __builtin_amdgcn_mfma_f32_16x16x32_f16(ah, wslh[ks], lga[m], 0, 0, 0);
        lga[m] = __builtin_amdgcn_mfma_f32_16x16x32_f16(al, wslh[ks], lga[m], 0, 0, 0);
        lga[m] = __builtin_amdgcn_mfma_f32_16x16x32_f16(ah, wsll[ks], lga[m], 0, 0, 0);
      }
#pragma unroll
    for (int m = 0; m < 4; ++m)
#pragma unroll
      for (int i = 0; i < 4; ++i)
        Lg[(m << 4) + (lg << 2) + i][(w << 4) + lr] = (lga[m][i] + bslv) * invt;
    __syncthreads();

    float e[4][4];
#pragma unroll
    for (int i = 0; i < 4; ++i) {
      const float4 lv4 = *(const float4*)&Lg[(ty << 2) + i][tx << 2];
      const float lrow[4] = {lv4.x, lv4.y, lv4.z, lv4.w};
      float mx = fmaxf(fmaxf(lrow[0], lrow[1]), fmaxf(lrow[2], lrow[3]));
      for (int d = 1; d < 16; d <<= 1) mx = fmaxf(mx, __shfl_xor(mx, d));
      float s = 0.f;
#pragma unroll
      for (int j = 0; j < 4; ++j) { e[i][j] = __expf(lrow[j] - mx); s += e[i][j]; }
      for (int d = 1; d < 16; d <<= 1) s += __shfl_xor(s, d);
      const float inv = 1.0f / s;
#pragma unroll
      for (int j = 0; j < 4; ++j) e[i][j] *= inv;
    }
#pragma unroll
    for (int i = 0; i < 4; ++i)
#pragma unroll
      for (int j = 0; j < 4; ++j) {
        const _Float16 hi = (_Float16)e[i][j];
        XMh[(ty << 2) + i][(tx << 2) + j] = hi;
        XMl[(ty << 2) + i][(tx << 2) + j] = (_Float16)(e[i][j] - (float)hi);
      }
    __syncthreads();

#pragma unroll
    for (int ks = 0; ks < 2; ++ks)
#pragma unroll
      for (int m = 0; m < 4; ++m) {
        const h8 ah = *(const h8*)&XMh[(m << 4) + lr][(ks << 5) + (lg << 3)];
        const h8 al = *(const h8*)&XMl[(m << 4) + lr][(ks << 5) + (lg << 3)];
#pragma unroll
        for (int n = 0; n < 4; ++n) {
          oacc[m][n] = __builtin_amdgcn_mfma_f32_16x16x32_f16(ah, wth[n][ks], oacc[m][n], 0, 0, 0);
          oacc[m][n] = __builtin_amdgcn_mfma_f32_16x16x32_f16(al, wth[n][ks], oacc[m][n], 0, 0, 0);
          oacc[m][n] = __builtin_amdgcn_mfma_f32_16x16x32_f16(ah, wtl[n][ks], oacc[m][n], 0, 0, 0);
        }
      }
    __syncthreads();
  }

#pragma unroll
  for (int n = 0; n < 4; ++n) {
    const float bov = bo[(w << 6) + (n << 4) + lr];
#pragma unroll
    for (int m = 0; m < 4; ++m)
#pragma unroll
      for (int i = 0; i < 4; ++i)
        out[((long)b * Nc + n0 + (m << 4) + (lg << 2) + i) * 256 + (w << 6) + (n << 4) + lr]
            = oacc[m][n][i] + bov;
  }
}

extern "C" void kernel_launch(void* const* d_in, const int* in_sizes, int n_in,
                              void* d_out, int out_size, void* d_ws, size_t ws_size,
                              hipStream_t stream)
{
  (void)in_sizes; (void)n_in; (void)out_size; (void)ws_size;
  const float* x    = (const float*)d_in[0];
  const float* xc   = (const float*)d_in[1];
  const float* Wfx  = (const float*)d_in[2];
  const float* bfx  = (const float*)d_in[3];
  const float* Wx   = (const float*)d_in[4];
  const float* bx   = (const float*)d_in[5];
  const float* Wsl  = (const float*)d_in[6];
  const float* bsl  = (const float*)d_in[7];
  const float* temp = (const float*)d_in[8];
  const float* Wq   = (const float*)d_in[9];
  const float* Wk   = (const float*)d_in[10];
  const float* Wv   = (const float*)d_in[11];
  const float* Wo   = (const float*)d_in[12];
  const float* bo   = (const float*)d_in[13];
  float* out = (float*)d_out;

  float* ws  = (float*)d_ws;
  float* Sx  = ws;                 // 2048
  float* Sc  = Sx + 2048;          // 2048
  float* TUx = Sc + 2048;          // 131072
  float* TUc = TUx + 131072;       // 131072
  float* OT  = TUc + 131072;       // 131072
  _Float16* WoTth = (_Float16*)(OT + 131072);   // 524288 f16 [bh][co][g]
  _Float16* WoTtl = WoTth + 524288;             // 524288 f16
  _Float16* Wxth  = WoTtl + 524288;             // 131072 f16 [col][k]
  _Float16* Wxtl  = Wxth + 131072;              // 131072 f16

  hipMemsetAsync(Sx, 0, (size_t)(2 * 2048 + 2 * 131072) * sizeof(float), stream);

  wxprep_kernel<<<dim3(4, 8), 256, 0, stream>>>(Wx, Wxth, Wxtl);
  project_token_kernel<<<dim3(16, 8, 8), 256, 0, stream>>>(
      x, xc, Wfx, bfx, Wx, bx, Wsl, bsl, temp, TUx, TUc, Sx, Sc);
  att_kernel<<<dim3(32), dim3(64), 0, stream>>>(TUx, TUc, Sx, Sc, Wq, Wk, Wv, OT);
  wofold_kernel<<<dim3(4, 32), 256, 0, stream>>>(OT, Wo, WoTth, WoTtl);
  outx_kernel<<<dim3(512, 4), 256, 0, stream>>>(x, Wxth, Wxtl, bx, Wsl, bsl, temp, WoTth, WoTtl, bo, out);
}